// Round 1
// baseline (1198.581 us; speedup 1.0000x reference)
//
#include <hip/hip_runtime.h>
#include <math.h>

// FactorizedSpectralConv2d: rfft2 -> mode-truncated complex channel mixing -> irfft2
// B=16, CIN=COUT=64, H=W=256, M1=M2=32. All fp32.
//
// Pipeline (all truncated DFTs as dense sums over the 64x32 live modes):
//  K0 tables : fp64-accurate twiddle tables into ws
//  K1 fwd_w  : per row, X1[row][kx<32] = sum_x x[row][x] e^{-2pi i kx x/256}  (x->x+128 parity fold)
//  K2 fwd_h  : per (b,c), F2[kyi<64][kx] = sum_y X1[y][kx] e^{-2pi i ky y/256}, ky = kyi<32?kyi:192+kyi
//  M1 mix1   : T[b,o,kyi,kx] = sum_i F2[b,i,kyi,kx] * W1(i,o,kyi)  (w1 top / w2 bot, scaled 1/65536)
//  M2 mix2   : G[b,o,kyi,kx] = sum_i T[b,i,kyi,kx] * WY(i,o,kx)
//  KC inv_h  : F3[y][kx] = sum_kyi G[kyi][kx] e^{+2pi i ky y/256}   (written into first 64 floats of out rows)
//  KD inv_w  : out[row][x] = a0 + 2*sum_{k=1..31}(a cos - b sin)    (x parity fold, reads own row then writes)

namespace {
constexpr int Bn = 16, Cn = 64;
constexpr int NROWS = 16 * 64 * 256;          // 262144
constexpr int NBC   = 16 * 64;                // 1024
// ws layout (float offsets)
constexpr long F2_OFF  = 0;                   // 4,194,304 floats ([b][i][kyi<64][kx<32] cplx)
constexpr long T_OFF   = 4194304;             // 4,194,304 floats
constexpr long TWA_OFF = 8388608;             // [x<128][k<32] cplx, e^{-i th}
constexpr long TWD_OFF = TWA_OFF + 8192;      // [k<32][x<128] cplx, e^{+i th}
constexpr long TW2_OFF = TWD_OFF + 8192;      // [y<256][kyi<64] cplx, e^{-i ky y}
constexpr long TWC_OFF = TW2_OFF + 32768;     // [kyi<64][y<256] cplx, e^{+i ky y}
}

__global__ __launch_bounds__(256) void fsc_tables(float* __restrict__ ws) {
  int idx = blockIdx.x * 256 + threadIdx.x;
  const double TP = 6.283185307179586476925286766559;
  if (idx < 4096) {                           // twA [x][k]
    int x = idx >> 5, k = idx & 31;
    double th = TP * ((k * x) & 255) / 256.0;
    ws[TWA_OFF + 2 * idx]     = (float)cos(th);
    ws[TWA_OFF + 2 * idx + 1] = (float)(-sin(th));
  } else if (idx < 8192) {                    // twD [k][x]
    int i2 = idx - 4096;
    int k = i2 >> 7, x = i2 & 127;
    double th = TP * ((k * x) & 255) / 256.0;
    ws[TWD_OFF + 2 * i2]     = (float)cos(th);
    ws[TWD_OFF + 2 * i2 + 1] = (float)sin(th);
  } else if (idx < 24576) {                   // tw2 [y][kyi]
    int i2 = idx - 8192;
    int y = i2 >> 6, kyi = i2 & 63;
    int ky = (kyi < 32) ? kyi : 192 + kyi;
    double th = TP * ((ky * y) & 255) / 256.0;
    ws[TW2_OFF + 2 * i2]     = (float)cos(th);
    ws[TW2_OFF + 2 * i2 + 1] = (float)(-sin(th));
  } else if (idx < 40960) {                   // twC [kyi][y]
    int i2 = idx - 24576;
    int kyi = i2 >> 8, y = i2 & 255;
    int ky = (kyi < 32) ? kyi : 192 + kyi;
    double th = TP * ((ky * y) & 255) / 256.0;
    ws[TWC_OFF + 2 * i2]     = (float)cos(th);
    ws[TWC_OFF + 2 * i2 + 1] = (float)sin(th);
  }
}

// K1: forward W-axis truncated DFT. Block = 32 rows. Thread: k = t&31, 4 rows.
__global__ __launch_bounds__(256) void fsc_fwd_w(const float* __restrict__ x,
                                                 float* __restrict__ F1,
                                                 const float* __restrict__ twA) {
  __shared__ float u[32][258];   // +2 pad: rows land on distinct banks
  int t = threadIdx.x;
  long rowbase = (long)blockIdx.x * 32;
  const float4* xv = (const float4*)(x + rowbase * 256);
  for (int i = t; i < 2048; i += 256) {
    float4 v = xv[i];
    int r = i >> 6, xc = (i & 63) << 2;
    u[r][xc] = v.x; u[r][xc + 1] = v.y; u[r][xc + 2] = v.z; u[r][xc + 3] = v.w;
  }
  __syncthreads();
  // in-place even/odd fold: u[r][x] = a+b, u[r][x+128] = a-b (each pair owned by one thread)
  for (int i = t; i < 4096; i += 256) {
    int r = i >> 7, xc = i & 127;
    float a = u[r][xc], b = u[r][xc + 128];
    u[r][xc] = a + b;
    u[r][xc + 128] = a - b;
  }
  __syncthreads();
  int k = t & 31, rg = t >> 5;
  int r0 = rg * 4;
  int uoff = (k & 1) ? 128 : 0;  // even k uses sum, odd k uses diff
  const float2* tw = (const float2*)twA;   // [x][k], (cos, -sin)
  float2 acc[4];
  #pragma unroll
  for (int j = 0; j < 4; ++j) { acc[j].x = 0.f; acc[j].y = 0.f; }
  #pragma unroll 4
  for (int xx = 0; xx < 128; ++xx) {
    float2 p = tw[xx * 32 + k];
    #pragma unroll
    for (int j = 0; j < 4; ++j) {
      float uv = u[r0 + j][uoff + xx];
      acc[j].x += uv * p.x;
      acc[j].y += uv * p.y;
    }
  }
  float2* f1o = (float2*)F1;
  long base = (rowbase + r0) * 32 + k;
  #pragma unroll
  for (int j = 0; j < 4; ++j) f1o[base + (long)j * 32] = acc[j];
}

// K2: forward H-axis truncated DFT. Block = one (b,c) image. Thread: kyi = t>>2, 8 kx.
__global__ __launch_bounds__(256) void fsc_fwd_h(const float* __restrict__ F1,
                                                 float* __restrict__ F2,
                                                 const float* __restrict__ tw2) {
  __shared__ float2 tile[4096];  // 128 y x 32 kx
  int t = threadIdx.x, bc = blockIdx.x;
  const float2* f1 = (const float2*)F1 + (long)bc * 8192;
  const float2* twp = (const float2*)tw2;  // [y][64]
  int kyi = t >> 2, kx0 = (t & 3) * 8;
  float2 acc[8];
  #pragma unroll
  for (int j = 0; j < 8; ++j) { acc[j].x = 0.f; acc[j].y = 0.f; }
  for (int half = 0; half < 2; ++half) {
    __syncthreads();
    for (int i = t; i < 4096; i += 256) tile[i] = f1[half * 4096 + i];
    __syncthreads();
    for (int yy = 0; yy < 128; ++yy) {
      float2 p = twp[(half * 128 + yy) * 64 + kyi];
      const float2* dr = &tile[yy * 32 + kx0];
      #pragma unroll
      for (int j = 0; j < 8; ++j) {
        float2 d = dr[j];
        acc[j].x += d.x * p.x - d.y * p.y;
        acc[j].y += d.x * p.y + d.y * p.x;
      }
    }
  }
  float2* o = (float2*)F2 + ((long)bc * 64 + kyi) * 32 + kx0;
  #pragma unroll
  for (int j = 0; j < 8; ++j) o[j] = acc[j];
}

// M1: T[b,o,kyi,kx] = sum_i F2[b,i,kyi,kx] * W1s(i,o,kyi). Block = (b, kyi).
__global__ __launch_bounds__(256) void fsc_mix1(const float* __restrict__ F2,
                                                float* __restrict__ T,
                                                const float* __restrict__ w1,
                                                const float* __restrict__ w2) {
  __shared__ float2 dt[2048];   // [i][kx]
  __shared__ float2 wt[4096];   // [i][o]
  int t = threadIdx.x;
  int b = blockIdx.x >> 6;
  int kyi = blockIdx.x & 63;
  const float* wsrc = (kyi < 32) ? w1 : w2;
  int m = (kyi < 32) ? kyi : (kyi - 32);
  const float2* f2 = (const float2*)F2;
  for (int i = t; i < 2048; i += 256) {
    int ci = i >> 5, kx = i & 31;
    dt[i] = f2[(((long)b * 64 + ci) * 64 + kyi) * 32 + kx];
  }
  const float SC = 1.0f / 65536.0f;   // ortho norm (1/sqrt(HW))^2 folded here once
  for (int i = t; i < 4096; i += 256) {
    int ci = i >> 6, o = i & 63;
    const float* wp = wsrc + (((long)ci * 64 + o) * 32 + m) * 2;
    wt[i].x = wp[0] * SC;
    wt[i].y = wp[1] * SC;
  }
  __syncthreads();
  int o = t & 63, kx0 = (t >> 6) * 8;
  float2 acc[8];
  #pragma unroll
  for (int j = 0; j < 8; ++j) { acc[j].x = 0.f; acc[j].y = 0.f; }
  for (int ci = 0; ci < 64; ++ci) {
    float2 w = wt[ci * 64 + o];
    const float2* dr = &dt[ci * 32 + kx0];
    #pragma unroll
    for (int j = 0; j < 8; ++j) {
      float2 d = dr[j];
      acc[j].x += d.x * w.x - d.y * w.y;
      acc[j].y += d.x * w.y + d.y * w.x;
    }
  }
  float2* o2 = (float2*)T + (((long)b * 64 + o) * 64 + kyi) * 32 + kx0;
  #pragma unroll
  for (int j = 0; j < 8; ++j) o2[j] = acc[j];
}

// M2: G[b,o,kyi,kx] = sum_i T[b,i,kyi,kx] * WY(i,o,kx). Block = (b, kx).
__global__ __launch_bounds__(256) void fsc_mix2(const float* __restrict__ T,
                                                float* __restrict__ G,
                                                const float* __restrict__ wy) {
  __shared__ float2 dt[4096];   // [i][kyi]
  __shared__ float2 wt[4096];   // [i][o]
  int t = threadIdx.x;
  int b = blockIdx.x >> 5;
  int kx = blockIdx.x & 31;
  const float2* tp = (const float2*)T;
  for (int i = t; i < 4096; i += 256) {
    int ci = i >> 6, kyi = i & 63;
    dt[i] = tp[(((long)b * 64 + ci) * 64 + kyi) * 32 + kx];
  }
  for (int i = t; i < 4096; i += 256) {
    int ci = i >> 6, o = i & 63;
    const float* wp = wy + (((long)ci * 64 + o) * 32 + kx) * 2;
    wt[i].x = wp[0];
    wt[i].y = wp[1];
  }
  __syncthreads();
  int o = t & 63, ky0 = (t >> 6) * 16;
  float2 acc[16];
  #pragma unroll
  for (int j = 0; j < 16; ++j) { acc[j].x = 0.f; acc[j].y = 0.f; }
  for (int ci = 0; ci < 64; ++ci) {
    float2 w = wt[ci * 64 + o];
    const float2* dr = &dt[ci * 64 + ky0];
    #pragma unroll
    for (int j = 0; j < 16; ++j) {
      float2 d = dr[j];
      acc[j].x += d.x * w.x - d.y * w.y;
      acc[j].y += d.x * w.y + d.y * w.x;
    }
  }
  float2* o2 = (float2*)G;
  #pragma unroll
  for (int j = 0; j < 16; ++j)
    o2[(((long)b * 64 + o) * 64 + (ky0 + j)) * 32 + kx] = acc[j];
}

// KC: inverse H-axis (full ifft over the 64 live ky). Block = (b,c). Thread = y.
// Writes F3 row into the first 64 floats of the corresponding out row.
__global__ __launch_bounds__(256) void fsc_inv_h(const float* __restrict__ G,
                                                 float* __restrict__ outp,
                                                 const float* __restrict__ twC) {
  __shared__ float2 gt[2048];   // [kyi][kx]
  int t = threadIdx.x, bc = blockIdx.x;
  const float2* gp = (const float2*)G + (long)bc * 2048;
  for (int i = t; i < 2048; i += 256) gt[i] = gp[i];
  __syncthreads();
  int y = t;
  const float2* twp = (const float2*)twC;  // [kyi][256]
  float2 acc[32];
  #pragma unroll
  for (int j = 0; j < 32; ++j) { acc[j].x = 0.f; acc[j].y = 0.f; }
  for (int kyi = 0; kyi < 64; ++kyi) {
    float2 p = twp[kyi * 256 + y];
    const float2* gr = &gt[kyi * 32];
    #pragma unroll
    for (int j = 0; j < 32; ++j) {
      float2 d = gr[j];
      acc[j].x += d.x * p.x - d.y * p.y;
      acc[j].y += d.x * p.y + d.y * p.x;
    }
  }
  float2* op = (float2*)(outp + ((long)bc * 256 + y) * 256);
  #pragma unroll
  for (int j = 0; j < 32; ++j) op[j] = acc[j];
}

// KD: inverse W-axis (irfft, 32 live bins). Block = 32 rows; reads its own rows' F3
// (first 64 floats) into LDS before overwriting with the 256 real outputs.
__global__ __launch_bounds__(256) void fsc_inv_w(float* __restrict__ outp,
                                                 const float* __restrict__ twD) {
  __shared__ float2 f3[32][32];   // [row][k]
  __shared__ float2 twt[4096];    // [k][x<128], (cos, +sin)
  int t = threadIdx.x;
  long rowbase = (long)blockIdx.x * 32;
  for (int i = t; i < 1024; i += 256) {
    int r = i >> 5, k = i & 31;
    f3[r][k] = ((const float2*)(outp + (rowbase + r) * 256))[k];
  }
  for (int i = t; i < 4096; i += 256) twt[i] = ((const float2*)twD)[i];
  __syncthreads();
  int xg = t & 31, r4 = t >> 5;   // rows r4, r4+8, r4+16, r4+24 ; x = xg + 32*j
  float eac[4][4], oac[4][4];
  #pragma unroll
  for (int rr = 0; rr < 4; ++rr)
    #pragma unroll
    for (int j = 0; j < 4; ++j) { eac[rr][j] = 0.f; oac[rr][j] = 0.f; }
  for (int k = 1; k < 32; ++k) {
    float2 twv[4];
    #pragma unroll
    for (int j = 0; j < 4; ++j) twv[j] = twt[k * 128 + xg + 32 * j];
    bool odd = (k & 1);
    #pragma unroll
    for (int rr = 0; rr < 4; ++rr) {
      float2 d = f3[r4 + rr * 8][k];
      #pragma unroll
      for (int j = 0; j < 4; ++j) {
        float v = d.x * twv[j].x - d.y * twv[j].y;   // Re(X * e^{+i th})
        if (odd) oac[rr][j] += v; else eac[rr][j] += v;
      }
    }
  }
  #pragma unroll
  for (int rr = 0; rr < 4; ++rr) {
    int r = r4 + rr * 8;
    float a0 = f3[r][0].x;
    float* orow = outp + (rowbase + r) * 256;
    #pragma unroll
    for (int j = 0; j < 4; ++j) {
      int xx = xg + 32 * j;
      orow[xx]       = a0 + 2.f * (eac[rr][j] + oac[rr][j]);
      orow[xx + 128] = a0 + 2.f * (eac[rr][j] - oac[rr][j]);
    }
  }
}

extern "C" void kernel_launch(void* const* d_in, const int* in_sizes, int n_in,
                              void* d_out, int out_size, void* d_ws, size_t ws_size,
                              hipStream_t stream) {
  const float* x  = (const float*)d_in[0];
  const float* w1 = (const float*)d_in[1];
  const float* w2 = (const float*)d_in[2];
  const float* wy = (const float*)d_in[3];
  float* out = (float*)d_out;
  float* ws  = (float*)d_ws;

  float* F1 = out;               // [row][k<32] cplx — exactly fills d_out, dead after fwd_h
  float* F2 = ws + F2_OFF;
  float* Tb = ws + T_OFF;
  float* G  = ws + F2_OFF;       // reuse F2 (dead after mix1)

  fsc_tables<<<160, 256, 0, stream>>>(ws);
  fsc_fwd_w<<<NROWS / 32, 256, 0, stream>>>(x, F1, ws + TWA_OFF);
  fsc_fwd_h<<<NBC, 256, 0, stream>>>(F1, F2, ws + TW2_OFF);
  fsc_mix1<<<Bn * 64, 256, 0, stream>>>(F2, Tb, w1, w2);
  fsc_mix2<<<Bn * 32, 256, 0, stream>>>(Tb, G, wy);
  fsc_inv_h<<<NBC, 256, 0, stream>>>(G, out, ws + TWC_OFF);
  fsc_inv_w<<<NROWS / 32, 256, 0, stream>>>(out, ws + TWD_OFF);
}